// Round 11
// baseline (381.918 us; speedup 1.0000x reference)
//
#include <hip/hip_runtime.h>
#include <cstdint>
#include <math.h>

#define B_ 4
#define S_ 2048
#define D_ 512
#define H_ 8
#define DK_ 64
#define SCALE 0.125f
#define KSTR 68   // K/V LDS row stride in bf16 (same stride class as PSTR=68, measured conflict-free)
#define PSTR 68   // Ps LDS row stride in bf16 (measured conflict-free)

using bfrag = __attribute__((ext_vector_type(8))) __bf16;
using b4    = __attribute__((ext_vector_type(4))) __bf16;
using f4    = __attribute__((ext_vector_type(4))) float;
using f2    = __attribute__((ext_vector_type(2))) float;
using f16v  = __attribute__((ext_vector_type(16))) float;
using u2    = __attribute__((ext_vector_type(2))) unsigned int;
using u4    = __attribute__((ext_vector_type(4))) unsigned int;

#define MFMA16(a, b, c) __builtin_amdgcn_mfma_f32_16x16x32_bf16(a, b, c, 0, 0, 0)
#define MFMA32(a, b, c) __builtin_amdgcn_mfma_f32_32x32x16_bf16(a, b, c, 0, 0, 0)

// ---------------------------------------------------------------------------
// All 4 weight transposes in one launch: grid (1024, 4).
// ---------------------------------------------------------------------------
__global__ __launch_bounds__(256) void wtr_all(
    const float* __restrict__ Wqkv, const float* __restrict__ Wout,
    __bf16* __restrict__ WqTh, __bf16* __restrict__ WqTl,
    __bf16* __restrict__ WkTh, __bf16* __restrict__ WkTl,
    __bf16* __restrict__ WvTh, __bf16* __restrict__ WoTh) {
  const int by = blockIdx.y;
  const int idx = blockIdx.x * 256 + threadIdx.x;  // 512*512
  const int k = idx & 511, n = idx >> 9;
  const float* W = (by == 3) ? Wout : Wqkv;
  const int ldw = (by == 3) ? 512 : 1536;
  const int c0 = (by == 3) ? 0 : by * 512;
  const float x = W[(size_t)k * ldw + c0 + n];
  const __bf16 h = (__bf16)x;
  __bf16* th = (by == 0) ? WqTh : (by == 1) ? WkTh : (by == 2) ? WvTh : WoTh;
  th[(size_t)n * 512 + k] = h;
  if (by < 2) {
    __bf16* tl = (by == 0) ? WqTl : WkTl;
    tl[(size_t)n * 512 + k] = (__bf16)(x - (float)h);
  }
}

// ---------------------------------------------------------------------------
// Merged Q+K projection: grid (8, 128, 2); z=0 -> Q, z=1 -> K.
// ---------------------------------------------------------------------------
__global__ __launch_bounds__(256) void qk_proj(
    const float* __restrict__ Zq, const float* __restrict__ Zkv,
    const __bf16* __restrict__ WqTh, const __bf16* __restrict__ WqTl,
    const __bf16* __restrict__ WkTh, const __bf16* __restrict__ WkTl,
    __bf16* __restrict__ Qh, __bf16* __restrict__ Ql,
    __bf16* __restrict__ Kh, __bf16* __restrict__ Kl) {
  __shared__ __bf16 Ash[64 * 40];
  __shared__ __bf16 Asl[64 * 40];
  __shared__ __bf16 Bsh[64 * 40];
  __shared__ __bf16 Bsl[64 * 40];

  const int zz = blockIdx.z;
  const float* A = zz ? Zkv : Zq;
  const __bf16* Bhp = zz ? WkTh : WqTh;
  const __bf16* Blp = zz ? WkTl : WqTl;
  __bf16* Oh = zz ? Kh : Qh;
  __bf16* Ol = zz ? Kl : Ql;

  const int tid = threadIdx.x;
  const int m0 = blockIdx.y * 64, n0 = blockIdx.x * 64;
  const int row = tid >> 2, seg = tid & 3;
  const int lane = tid & 63, wv = tid >> 6;
  const int wm = (wv & 1) * 32, wn = (wv >> 1) * 32;
  const int qd = lane >> 4, ln = lane & 15;

  f4 acc[2][2];
#pragma unroll
  for (int i = 0; i < 2; i++)
#pragma unroll
    for (int j = 0; j < 2; j++)
#pragma unroll
      for (int r = 0; r < 4; r++) acc[i][j][r] = 0.f;

  for (int kt = 0; kt < 512; kt += 32) {
    const size_t abase = (size_t)(m0 + row) * 512 + kt + seg * 8;
    const size_t bbase = (size_t)(n0 + row) * 512 + kt + seg * 8;
    float4 a0 = *(const float4*)&A[abase];
    float4 a1 = *(const float4*)&A[abase + 4];
    float4 b0 = *(const float4*)&Bhp[bbase];
    float4 bl0 = *(const float4*)&Blp[bbase];
    __syncthreads();
    {
      float x[8] = {a0.x, a0.y, a0.z, a0.w, a1.x, a1.y, a1.z, a1.w};
      bfrag h, l;
#pragma unroll
      for (int j = 0; j < 8; j++) {
        h[j] = (__bf16)x[j];
        l[j] = (__bf16)(x[j] - (float)h[j]);
      }
      *(bfrag*)&Ash[row * 40 + seg * 8] = h;
      *(bfrag*)&Asl[row * 40 + seg * 8] = l;
    }
    *(float4*)&Bsh[row * 40 + seg * 8] = b0;
    *(float4*)&Bsl[row * 40 + seg * 8] = bl0;
    __syncthreads();

    bfrag ah[2], al[2], bh[2], bl[2];
#pragma unroll
    for (int mi = 0; mi < 2; mi++) {
      ah[mi] = *(bfrag*)&Ash[(wm + mi * 16 + ln) * 40 + qd * 8];
      al[mi] = *(bfrag*)&Asl[(wm + mi * 16 + ln) * 40 + qd * 8];
    }
#pragma unroll
    for (int ni = 0; ni < 2; ni++) {
      bh[ni] = *(bfrag*)&Bsh[(wn + ni * 16 + ln) * 40 + qd * 8];
      bl[ni] = *(bfrag*)&Bsl[(wn + ni * 16 + ln) * 40 + qd * 8];
    }
#pragma unroll
    for (int mi = 0; mi < 2; mi++)
#pragma unroll
      for (int ni = 0; ni < 2; ni++) {
        acc[mi][ni] = MFMA16(ah[mi], bh[ni], acc[mi][ni]);
        acc[mi][ni] = MFMA16(ah[mi], bl[ni], acc[mi][ni]);
        acc[mi][ni] = MFMA16(al[mi], bh[ni], acc[mi][ni]);
      }
  }

#pragma unroll
  for (int mi = 0; mi < 2; mi++)
#pragma unroll
    for (int ni = 0; ni < 2; ni++)
#pragma unroll
      for (int r = 0; r < 4; r++) {
        const int mrow = m0 + wm + mi * 16 + qd * 4 + r;
        const int ncol = n0 + wn + ni * 16 + ln;
        const float c = acc[mi][ni][r];
        const int b = mrow >> 11, s = mrow & (S_ - 1);
        const int h = ncol >> 6, dk = ncol & 63;
        const size_t o = (((size_t)b * H_ + h) * S_ + s) * DK_ + dk;
        __bf16 hh = (__bf16)c;
        Oh[o] = hh;
        Ol[o] = (__bf16)(c - (float)hh);
      }
}

// ---------------------------------------------------------------------------
// Split-bf16 MFMA GEMM (template kept for V^T MODE2 and out MODE0).
// ---------------------------------------------------------------------------
template <bool AF32, bool BF32, bool LO, int MODE>
__global__ __launch_bounds__(256) void gemm_mfma(
    const void* __restrict__ Ap, const void* __restrict__ Bp, const void* __restrict__ Blop,
    float* __restrict__ Cf, __bf16* __restrict__ Oh, __bf16* __restrict__ Ol) {
  __shared__ __bf16 Ash[64 * 40];
  __shared__ __bf16 Asl[64 * 40];
  __shared__ __bf16 Bsh[64 * 40];
  __shared__ __bf16 Bsl[64 * 40];

  const int tid = threadIdx.x;
  const int m0 = blockIdx.y * 64, n0 = blockIdx.x * 64;
  const int row = tid >> 2, seg = tid & 3;
  const int lane = tid & 63, wv = tid >> 6;
  const int wm = (wv & 1) * 32, wn = (wv >> 1) * 32;
  const int qd = lane >> 4, ln = lane & 15;

  f4 acc[2][2];
#pragma unroll
  for (int i = 0; i < 2; i++)
#pragma unroll
    for (int j = 0; j < 2; j++)
#pragma unroll
      for (int r = 0; r < 4; r++) acc[i][j][r] = 0.f;

  for (int kt = 0; kt < 512; kt += 32) {
    const size_t abase = (size_t)(m0 + row) * 512 + kt + seg * 8;
    const size_t bbase = (size_t)(n0 + row) * 512 + kt + seg * 8;
    float4 a0, a1, b0, b1, bl0;
    if constexpr (AF32) {
      const float* A = (const float*)Ap;
      a0 = *(const float4*)&A[abase];
      a1 = *(const float4*)&A[abase + 4];
    } else {
      const __bf16* A = (const __bf16*)Ap;
      a0 = *(const float4*)&A[abase];
    }
    if constexpr (BF32) {
      const float* Bm = (const float*)Bp;
      b0 = *(const float4*)&Bm[bbase];
      b1 = *(const float4*)&Bm[bbase + 4];
    } else {
      const __bf16* Bm = (const __bf16*)Bp;
      b0 = *(const float4*)&Bm[bbase];
      if constexpr (LO) {
        const __bf16* Bl = (const __bf16*)Blop;
        bl0 = *(const float4*)&Bl[bbase];
      }
    }
    __syncthreads();
    if constexpr (AF32) {
      float x[8] = {a0.x, a0.y, a0.z, a0.w, a1.x, a1.y, a1.z, a1.w};
      bfrag h, l;
#pragma unroll
      for (int j = 0; j < 8; j++) {
        h[j] = (__bf16)x[j];
        l[j] = (__bf16)(x[j] - (float)h[j]);
      }
      *(bfrag*)&Ash[row * 40 + seg * 8] = h;
      if constexpr (LO) *(bfrag*)&Asl[row * 40 + seg * 8] = l;
    } else {
      *(float4*)&Ash[row * 40 + seg * 8] = a0;
    }
    if constexpr (BF32) {
      float x[8] = {b0.x, b0.y, b0.z, b0.w, b1.x, b1.y, b1.z, b1.w};
      bfrag h;
#pragma unroll
      for (int j = 0; j < 8; j++) h[j] = (__bf16)x[j];
      *(bfrag*)&Bsh[row * 40 + seg * 8] = h;
    } else {
      *(float4*)&Bsh[row * 40 + seg * 8] = b0;
      if constexpr (LO) *(float4*)&Bsl[row * 40 + seg * 8] = bl0;
    }
    __syncthreads();

    bfrag ah[2], al[2], bh[2], bl[2];
#pragma unroll
    for (int mi = 0; mi < 2; mi++) {
      ah[mi] = *(bfrag*)&Ash[(wm + mi * 16 + ln) * 40 + qd * 8];
      if constexpr (LO) al[mi] = *(bfrag*)&Asl[(wm + mi * 16 + ln) * 40 + qd * 8];
    }
#pragma unroll
    for (int ni = 0; ni < 2; ni++) {
      bh[ni] = *(bfrag*)&Bsh[(wn + ni * 16 + ln) * 40 + qd * 8];
      if constexpr (LO) bl[ni] = *(bfrag*)&Bsl[(wn + ni * 16 + ln) * 40 + qd * 8];
    }
#pragma unroll
    for (int mi = 0; mi < 2; mi++)
#pragma unroll
      for (int ni = 0; ni < 2; ni++) {
        acc[mi][ni] = MFMA16(ah[mi], bh[ni], acc[mi][ni]);
        if constexpr (LO) {
          acc[mi][ni] = MFMA16(ah[mi], bl[ni], acc[mi][ni]);
          acc[mi][ni] = MFMA16(al[mi], bh[ni], acc[mi][ni]);
        }
      }
  }

#pragma unroll
  for (int mi = 0; mi < 2; mi++)
#pragma unroll
    for (int ni = 0; ni < 2; ni++)
#pragma unroll
      for (int r = 0; r < 4; r++) {
        const int mrow = m0 + wm + mi * 16 + qd * 4 + r;
        const int ncol = n0 + wn + ni * 16 + ln;
        const float c = acc[mi][ni][r];
        if constexpr (MODE == 0) {
          Cf[(size_t)mrow * 512 + ncol] = c;
        } else if constexpr (MODE == 1) {
          const int b = mrow >> 11, s = mrow & (S_ - 1);
          const int h = ncol >> 6, dk = ncol & 63;
          const size_t o = (((size_t)b * H_ + h) * S_ + s) * DK_ + dk;
          __bf16 hh = (__bf16)c;
          Oh[o] = hh;
          Ol[o] = (__bf16)(c - (float)hh);
        } else {  // MODE 2: V^T
          const int h = mrow >> 6, dk = mrow & 63;
          const int b = ncol >> 11, s = ncol & (S_ - 1);
          Oh[(((size_t)b * H_ + h) * DK_ + dk) * S_ + s] = (__bf16)c;
        }
      }
}

// ---------------------------------------------------------------------------
// Fused flash attention — R4 frozen PER-WAVE body, QBLK=256 / 8-wave blocks.
// R10 established: body frozen (139.5 µs), occupancy/VALU/structure levers
// all refuted. Remaining untested mechanism: staging+K/V-fetch amortization.
// Block = 512 threads (8 waves x 32 q = 256 q); grid (S/256, B*H) = 256.
// - K/V logical HBM reads halve (8 blocks/head vs 16) -> FETCH drop expected.
// - One K/V stage serves 2x the q; per-thread staging work halves.
// - Per-wave loop body is BIT-IDENTICAL to the frozen R4 body.
// LDS: KSTR 84->68 so 256 Ps rows fit: 3*64*68*2 + 256*68*2 + 1024 = 61952 B
// (68 is PSTR's measured-conflict-free stride class; guard counter:
// SQ_LDS_BANK_CONFLICT, currently 0).
// Risk (pre-committed): 1 block/CU loses inter-block barrier overlap; if dur
// lands 150-170 instead of 125-132, revert to R10 geometry.
// ---------------------------------------------------------------------------
__global__ __launch_bounds__(512) void attn_fctx(
    const __bf16* __restrict__ Qh_, const __bf16* __restrict__ Ql_,
    const __bf16* __restrict__ Kh_, const __bf16* __restrict__ Kl_,
    const __bf16* __restrict__ VT, const float* __restrict__ mask,
    __bf16* __restrict__ CTXb, float* __restrict__ MR, float* __restrict__ LR,
    unsigned char* __restrict__ E, float* __restrict__ MT) {
  __shared__ __bf16 Ksh[64 * KSTR];
  __shared__ __bf16 Ksl[64 * KSTR];
  __shared__ __bf16 Vs[64 * KSTR];
  __shared__ __bf16 Ps[256 * PSTR];
  __shared__ float als[256];
  const int tid = threadIdx.x, lane = tid & 63, wv = tid >> 6;  // wv 0..7
  const int l31 = lane & 31, kh = lane >> 5;
  const int qd = lane >> 4, ln = lane & 15;
  const int bh = blockIdx.y;
  const int q0b = blockIdx.x * 256;
  const int q0w = q0b + wv * 32;
  const int srow = tid >> 3, sseg = tid & 7;  // 64 rows x 8 segs (8 bf16 each)

  // Q fragments (B-operand, 32x32x16): n = q = l31, k = ks*16 + kh*8 + j
  bfrag qhf[4], qlf[4];
#pragma unroll
  for (int ks = 0; ks < 4; ks++) {
    const size_t qb = ((size_t)bh * S_ + q0w + l31) * DK_ + ks * 16 + kh * 8;
    qhf[ks] = *(const bfrag*)&Qh_[qb];
    qlf[ks] = *(const bfrag*)&Ql_[qb];
  }

  float m = -3.0e38f, l = 0.f;   // per lane: q = q0w + l31 (dup across halves)
  f4 cacc[2][4];                  // [mt][nt] — PV 16-shape accumulators
#pragma unroll
  for (int mt = 0; mt < 2; mt++)
#pragma unroll
    for (int nt = 0; nt < 4; nt++)
#pragma unroll
      for (int r = 0; r < 4; r++) cacc[mt][nt][r] = 0.f;

  // prefetch tile 0 (one float4 per array per thread: 512 threads cover 64x64)
  float4 h0, l0, v0;
  {
    const size_t kb = ((size_t)bh * S_ + srow) * DK_ + sseg * 8;
    const size_t vb = ((size_t)bh * DK_ + srow) * S_ + sseg * 8;
    h0 = *(const float4*)&Kh_[kb];
    l0 = *(const float4*)&Kl_[kb];
    v0 = *(const float4*)&VT[vb];
  }

  for (int kt = 0; kt < S_; kt += 64) {
    __syncthreads();
    *(float4*)&Ksh[srow * KSTR + sseg * 8] = h0;
    *(float4*)&Ksl[srow * KSTR + sseg * 8] = l0;
    *(float4*)&Vs[srow * KSTR + sseg * 8] = v0;
    __syncthreads();

    // mask, transposed order: entry (q = q0w+l31, kv = kt + t*32 + g*8 + 4*kh + i)
    f4 mk[2][4];
#pragma unroll
    for (int t = 0; t < 2; t++)
#pragma unroll
      for (int g = 0; g < 4; g++)
        mk[t][g] = *(const f4*)&mask[(size_t)(q0w + l31) * S_ + kt + t * 32 + g * 8 + 4 * kh];

    // prefetch next tile
    if (kt + 64 < S_) {
      const size_t kb = ((size_t)bh * S_ + kt + 64 + srow) * DK_ + sseg * 8;
      const size_t vb = ((size_t)bh * DK_ + srow) * S_ + kt + 64 + sseg * 8;
      h0 = *(const float4*)&Kh_[kb];
      l0 = *(const float4*)&Kl_[kb];
      v0 = *(const float4*)&VT[vb];
    }

    // ---- z^T = K·Q^T, 32x32x16 split-3: 16 b128 reads, 24 MFMAs, 32 q ----
    f16v z[2];
#pragma unroll
    for (int t = 0; t < 2; t++)
#pragma unroll
      for (int r = 0; r < 16; r++) z[t][r] = 0.f;
#pragma unroll
    for (int t = 0; t < 2; t++)
#pragma unroll
      for (int ks = 0; ks < 4; ks++) {
        bfrag kbh = *(bfrag*)&Ksh[(t * 32 + l31) * KSTR + ks * 16 + kh * 8];
        bfrag kbl = *(bfrag*)&Ksl[(t * 32 + l31) * KSTR + ks * 16 + kh * 8];
        z[t] = MFMA32(kbh, qhf[ks], z[t]);
        z[t] = MFMA32(kbl, qhf[ks], z[t]);
        z[t] = MFMA32(kbh, qlf[ks], z[t]);
      }

    // ---- scale + mask in place ----
#pragma unroll
    for (int t = 0; t < 2; t++)
#pragma unroll
      for (int r = 0; r < 16; r++)
        z[t][r] = fmaf(z[t][r], SCALE, mk[t][r >> 2][r & 3]);

    // ---- online softmax: per-lane q column, 1 cross-lane reduce ----
    float tm = z[0][0];
#pragma unroll
    for (int t = 0; t < 2; t++)
#pragma unroll
      for (int r = 0; r < 16; r++) tm = fmaxf(tm, z[t][r]);
    tm = fmaxf(tm, __shfl_xor(tm, 32, 64));
    const float nm = fmaxf(m, tm);
    const float al = __expf(m - nm);
    m = nm;
    if (lane < 32) als[wv * 32 + lane] = al;

    float ls = 0.f;
#pragma unroll
    for (int t = 0; t < 2; t++)
#pragma unroll
      for (int g = 0; g < 4; g++) {
        const float e0 = __expf(z[t][g * 4 + 0] - nm);
        const float e1 = __expf(z[t][g * 4 + 1] - nm);
        const float e2 = __expf(z[t][g * 4 + 2] - nm);
        const float e3 = __expf(z[t][g * 4 + 3] - nm);
        ls += (e0 + e1) + (e2 + e3);
        b4 pk;
        pk[0] = (__bf16)e0; pk[1] = (__bf16)e1;
        pk[2] = (__bf16)e2; pk[3] = (__bf16)e3;
        *(b4*)&Ps[(wv * 32 + l31) * PSTR + t * 32 + g * 8 + 4 * kh] = pk;
      }
    l = l * al + ls;

    if (lane < 32)
      MT[((size_t)bh * 32 + (kt >> 6)) * S_ + q0w + lane] = m;

    // ---- rescale cacc with alpha from LDS (row q = mt*16 + qd*4 + r) ----
#pragma unroll
    for (int mt = 0; mt < 2; mt++) {
      f4 av = *(f4*)&als[wv * 32 + mt * 16 + qd * 4];
#pragma unroll
      for (int nt = 0; nt < 4; nt++)
#pragma unroll
        for (int r = 0; r < 4; r++) cacc[mt][nt][r] *= av[r];
    }

    // ---- PV (16 MFMA, 16-shape): P m=q (2 tiles), V n=d (4 tiles), k=kv ----
    bfrag pa[2][2];
#pragma unroll
    for (int mt = 0; mt < 2; mt++)
#pragma unroll
      for (int ks = 0; ks < 2; ks++)
        pa[mt][ks] = *(bfrag*)&Ps[(wv * 32 + mt * 16 + ln) * PSTR + ks * 32 + qd * 8];
#pragma unroll
    for (int nt = 0; nt < 4; nt++)
#pragma unroll
      for (int ks = 0; ks < 2; ks++) {
        bfrag vbf = *(bfrag*)&Vs[(nt * 16 + ln) * KSTR + ks * 32 + qd * 8];
#pragma unroll
        for (int mt = 0; mt < 2; mt++)
          cacc[mt][nt] = MFMA16(pa[mt][ks], vbf, cacc[mt][nt]);
      }

    // ---- E copy: Ps rows -> global fp8 e4m3 (vectorized, coalesced) ----
#pragma unroll
    for (int c = 0; c < 4; c++) {
      const int row = wv * 32 + (lane >> 3) + c * 8;
      const int ch = lane & 7;
      bfrag pv = *(bfrag*)&Ps[row * PSTR + ch * 8];
      int lo = 0, hi = 0;
      lo = __builtin_amdgcn_cvt_pk_fp8_f32((float)pv[0], (float)pv[1], lo, 0);
      lo = __builtin_amdgcn_cvt_pk_fp8_f32((float)pv[2], (float)pv[3], lo, 1);
      hi = __builtin_amdgcn_cvt_pk_fp8_f32((float)pv[4], (float)pv[5], hi, 0);
      hi = __builtin_amdgcn_cvt_pk_fp8_f32((float)pv[6], (float)pv[7], hi, 1);
      u2 ev;
      ev.x = (unsigned int)lo;
      ev.y = (unsigned int)hi;
      __builtin_nontemporal_store(
          ev, (u2*)&E[((size_t)bh * S_ + q0b + row) * S_ + kt + ch * 8]);
    }
  }

  // ---- epilogue ----
  l += __shfl_xor(l, 32, 64);
  if (lane < 32) {
    MR[(size_t)bh * S_ + q0w + lane] = m;
    LR[(size_t)bh * S_ + q0w + lane] = l;
    als[wv * 32 + lane] = 1.0f / l;
  }
  const int b = bh >> 3, h = bh & 7;
#pragma unroll
  for (int mt = 0; mt < 2; mt++) {
    f4 iv = *(f4*)&als[wv * 32 + mt * 16 + qd * 4];
#pragma unroll
    for (int nt = 0; nt < 4; nt++)
#pragma unroll
      for (int r = 0; r < 4; r++)
        CTXb[((size_t)b * S_ + q0w + mt * 16 + qd * 4 + r) * D_ + h * DK_ + nt * 16 + ln] =
            (__bf16)(cacc[mt][nt][r] * iv[r]);
  }
}

// ---------------------------------------------------------------------------
// mean = (1/8) sum_h E * exp(MT - m_fin) / l_fin  — bandwidth kernel.
// R8's coalesced layout (verified, ~20 µs gain): block = 8 q x 32 k-segments;
// each lane loads 16 B of E -> 512 B contiguous per wave per head; writes
// 16 f32/lane -> 2 KB contiguous per wave. Grid (S/8, B, S/512).
// E fp8 e4m3; MT/MR natural-log domain.
// ---------------------------------------------------------------------------
__global__ __launch_bounds__(256) void mean_rescale(
    const unsigned char* __restrict__ E, const float* __restrict__ MT,
    const float* __restrict__ MR, const float* __restrict__ LR,
    float* __restrict__ meanout) {
  const int t = threadIdx.x;
  const int qr = t >> 5, sk = t & 31;
  const int b = blockIdx.y;
  const int qg = blockIdx.x * 8 + qr;
  const int k0 = blockIdx.z * 512 + sk * 16;
  const int tk = k0 >> 6;

  float acc[16];
#pragma unroll
  for (int j = 0; j < 16; j++) acc[j] = 0.f;

#pragma unroll
  for (int h = 0; h < H_; h++) {
    const int bh = b * H_ + h;
    const float mf = MR[(size_t)bh * S_ + qg];
    const float il = 1.0f / LR[(size_t)bh * S_ + qg];
    const float mt = MT[((size_t)bh * 32 + tk) * S_ + qg];
    const float sc = __expf(mt - mf) * il;
    u4 e = __builtin_nontemporal_load(
        (const u4*)&E[((size_t)bh * S_ + qg) * S_ + k0]);
#pragma unroll
    for (int wd = 0; wd < 4; wd++) {
      f2 plo = __builtin_amdgcn_cvt_pk_f32_fp8((int)e[wd], 0);
      f2 phi = __builtin_amdgcn_cvt_pk_f32_fp8((int)e[wd], 1);
      acc[wd * 4 + 0] += plo.x * sc;
      acc[wd * 4 + 1] += plo.y * sc;
      acc[wd * 4 + 2] += phi.x * sc;
      acc[wd * 4 + 3] += phi.y * sc;
    }
  }

  float* mp = &meanout[((size_t)b * S_ + qg) * S_ + k0];
#pragma unroll
  for (int wd = 0; wd < 4; wd++) {
    f4 o;
    o[0] = acc[wd * 4 + 0] * 0.125f;
    o[1] = acc[wd * 4 + 1] * 0.125f;
    o[2] = acc[wd * 4 + 2] * 0.125f;
    o[3] = acc[wd * 4 + 3] * 0.125f;
    *(f4*)&mp[wd * 4] = o;
  }
}

// ---------------------------------------------------------------------------
extern "C" void kernel_launch(void* const* d_in, const int* in_sizes, int n_in,
                              void* d_out, int out_size, void* d_ws, size_t ws_size,
                              hipStream_t stream) {
  (void)in_sizes; (void)n_in; (void)out_size; (void)ws_size;
  const float* Zq = (const float*)d_in[0];
  const float* Zkv = (const float*)d_in[1];
  const float* mask = (const float*)d_in[2];
  const float* Wqkv = (const float*)d_in[3];
  const float* Wout = (const float*)d_in[4];

  float* out = (float*)d_out;                // [B,S,D]
  float* mean = out + (size_t)B_ * S_ * D_;  // [B,S,S]

  char* w = (char*)d_ws;
  const size_t WSZ = 512 * 512 * sizeof(__bf16);
  const size_t QSZ = (size_t)B_ * H_ * S_ * DK_ * sizeof(__bf16);
  __bf16* WqTh = (__bf16*)w; w += WSZ;
  __bf16* WqTl = (__bf16*)w; w += WSZ;
  __bf16* WkTh = (__bf16*)w; w += WSZ;
  __bf16* WkTl = (__bf16*)w; w += WSZ;
  __bf16* WvTh = (__bf16*)w; w += WSZ;
  __bf16* WoTh = (__bf16*)w; w += WSZ;
  __bf16* Qh = (__bf16*)w; w += QSZ;
  __bf16* Ql = (__bf16*)w; w += QSZ;
  __bf16* Kh = (__bf16*)w; w += QSZ;
  __bf16* Kl = (__bf16*)w; w += QSZ;
  __bf16* VTh = (__bf16*)w; w += QSZ;
  __bf16* CTXb = (__bf16*)w; w += QSZ;
  float* MR = (float*)w; w += (size_t)B_ * H_ * S_ * sizeof(float);
  float* LR = (float*)w; w += (size_t)B_ * H_ * S_ * sizeof(float);
  float* MT = (float*)w; w += (size_t)B_ * H_ * 32 * S_ * sizeof(float);       // 8.4 MB
  unsigned char* E = (unsigned char*)w; w += (size_t)B_ * H_ * S_ * S_;        // 134 MB (fp8)

  wtr_all<<<dim3(1024, 4), 256, 0, stream>>>(Wqkv, Wout, WqTh, WqTl, WkTh, WkTl, WvTh, WoTh);

  qk_proj<<<dim3(8, 128, 2), 256, 0, stream>>>(
      Zq, Zkv, WqTh, WqTl, WkTh, WkTl, Qh, Ql, Kh, Kl);
  gemm_mfma<false, true, false, 2><<<dim3(128, 8), 256, 0, stream>>>(
      WvTh, Zkv, nullptr, nullptr, VTh, nullptr);

  attn_fctx<<<dim3(8, 32), 512, 0, stream>>>(Qh, Ql, Kh, Kl, VTh, mask, CTXb, MR, LR, E, MT);
  mean_rescale<<<dim3(256, 4, 4), 256, 0, stream>>>(E, MT, MR, LR, mean);

  gemm_mfma<false, false, false, 0><<<dim3(8, 128), 256, 0, stream>>>(
      CTXb, WoTh, nullptr, out, nullptr, nullptr);
}

// Round 12
// 369.287 us; speedup vs baseline: 1.0342x; 1.0342x over previous
//
#include <hip/hip_runtime.h>
#include <cstdint>
#include <math.h>

#define B_ 4
#define S_ 2048
#define D_ 512
#define H_ 8
#define DK_ 64
#define SCALE 0.125f
#define KSTR 84   // K/V LDS row stride in bf16 (measured conflict-free)
#define PSTR 68   // Ps LDS row stride in bf16 (measured conflict-free)

using bfrag = __attribute__((ext_vector_type(8))) __bf16;
using b4    = __attribute__((ext_vector_type(4))) __bf16;
using f4    = __attribute__((ext_vector_type(4))) float;
using f2    = __attribute__((ext_vector_type(2))) float;
using f16v  = __attribute__((ext_vector_type(16))) float;
using u2    = __attribute__((ext_vector_type(2))) unsigned int;
using u4    = __attribute__((ext_vector_type(4))) unsigned int;

#define MFMA16(a, b, c) __builtin_amdgcn_mfma_f32_16x16x32_bf16(a, b, c, 0, 0, 0)
#define MFMA32(a, b, c) __builtin_amdgcn_mfma_f32_32x32x16_bf16(a, b, c, 0, 0, 0)

// ---------------------------------------------------------------------------
// All 4 weight transposes in one launch: grid (1024, 4).
// ---------------------------------------------------------------------------
__global__ __launch_bounds__(256) void wtr_all(
    const float* __restrict__ Wqkv, const float* __restrict__ Wout,
    __bf16* __restrict__ WqTh, __bf16* __restrict__ WqTl,
    __bf16* __restrict__ WkTh, __bf16* __restrict__ WkTl,
    __bf16* __restrict__ WvTh, __bf16* __restrict__ WoTh) {
  const int by = blockIdx.y;
  const int idx = blockIdx.x * 256 + threadIdx.x;  // 512*512
  const int k = idx & 511, n = idx >> 9;
  const float* W = (by == 3) ? Wout : Wqkv;
  const int ldw = (by == 3) ? 512 : 1536;
  const int c0 = (by == 3) ? 0 : by * 512;
  const float x = W[(size_t)k * ldw + c0 + n];
  const __bf16 h = (__bf16)x;
  __bf16* th = (by == 0) ? WqTh : (by == 1) ? WkTh : (by == 2) ? WvTh : WoTh;
  th[(size_t)n * 512 + k] = h;
  if (by < 2) {
    __bf16* tl = (by == 0) ? WqTl : WkTl;
    tl[(size_t)n * 512 + k] = (__bf16)(x - (float)h);
  }
}

// ---------------------------------------------------------------------------
// Merged Q+K projection: grid (8, 128, 2); z=0 -> Q, z=1 -> K.
// ---------------------------------------------------------------------------
__global__ __launch_bounds__(256) void qk_proj(
    const float* __restrict__ Zq, const float* __restrict__ Zkv,
    const __bf16* __restrict__ WqTh, const __bf16* __restrict__ WqTl,
    const __bf16* __restrict__ WkTh, const __bf16* __restrict__ WkTl,
    __bf16* __restrict__ Qh, __bf16* __restrict__ Ql,
    __bf16* __restrict__ Kh, __bf16* __restrict__ Kl) {
  __shared__ __bf16 Ash[64 * 40];
  __shared__ __bf16 Asl[64 * 40];
  __shared__ __bf16 Bsh[64 * 40];
  __shared__ __bf16 Bsl[64 * 40];

  const int zz = blockIdx.z;
  const float* A = zz ? Zkv : Zq;
  const __bf16* Bhp = zz ? WkTh : WqTh;
  const __bf16* Blp = zz ? WkTl : WqTl;
  __bf16* Oh = zz ? Kh : Qh;
  __bf16* Ol = zz ? Kl : Ql;

  const int tid = threadIdx.x;
  const int m0 = blockIdx.y * 64, n0 = blockIdx.x * 64;
  const int row = tid >> 2, seg = tid & 3;
  const int lane = tid & 63, wv = tid >> 6;
  const int wm = (wv & 1) * 32, wn = (wv >> 1) * 32;
  const int qd = lane >> 4, ln = lane & 15;

  f4 acc[2][2];
#pragma unroll
  for (int i = 0; i < 2; i++)
#pragma unroll
    for (int j = 0; j < 2; j++)
#pragma unroll
      for (int r = 0; r < 4; r++) acc[i][j][r] = 0.f;

  for (int kt = 0; kt < 512; kt += 32) {
    const size_t abase = (size_t)(m0 + row) * 512 + kt + seg * 8;
    const size_t bbase = (size_t)(n0 + row) * 512 + kt + seg * 8;
    float4 a0 = *(const float4*)&A[abase];
    float4 a1 = *(const float4*)&A[abase + 4];
    float4 b0 = *(const float4*)&Bhp[bbase];
    float4 bl0 = *(const float4*)&Blp[bbase];
    __syncthreads();
    {
      float x[8] = {a0.x, a0.y, a0.z, a0.w, a1.x, a1.y, a1.z, a1.w};
      bfrag h, l;
#pragma unroll
      for (int j = 0; j < 8; j++) {
        h[j] = (__bf16)x[j];
        l[j] = (__bf16)(x[j] - (float)h[j]);
      }
      *(bfrag*)&Ash[row * 40 + seg * 8] = h;
      *(bfrag*)&Asl[row * 40 + seg * 8] = l;
    }
    *(float4*)&Bsh[row * 40 + seg * 8] = b0;
    *(float4*)&Bsl[row * 40 + seg * 8] = bl0;
    __syncthreads();

    bfrag ah[2], al[2], bh[2], bl[2];
#pragma unroll
    for (int mi = 0; mi < 2; mi++) {
      ah[mi] = *(bfrag*)&Ash[(wm + mi * 16 + ln) * 40 + qd * 8];
      al[mi] = *(bfrag*)&Asl[(wm + mi * 16 + ln) * 40 + qd * 8];
    }
#pragma unroll
    for (int ni = 0; ni < 2; ni++) {
      bh[ni] = *(bfrag*)&Bsh[(wn + ni * 16 + ln) * 40 + qd * 8];
      bl[ni] = *(bfrag*)&Bsl[(wn + ni * 16 + ln) * 40 + qd * 8];
    }
#pragma unroll
    for (int mi = 0; mi < 2; mi++)
#pragma unroll
      for (int ni = 0; ni < 2; ni++) {
        acc[mi][ni] = MFMA16(ah[mi], bh[ni], acc[mi][ni]);
        acc[mi][ni] = MFMA16(ah[mi], bl[ni], acc[mi][ni]);
        acc[mi][ni] = MFMA16(al[mi], bh[ni], acc[mi][ni]);
      }
  }

#pragma unroll
  for (int mi = 0; mi < 2; mi++)
#pragma unroll
    for (int ni = 0; ni < 2; ni++)
#pragma unroll
      for (int r = 0; r < 4; r++) {
        const int mrow = m0 + wm + mi * 16 + qd * 4 + r;
        const int ncol = n0 + wn + ni * 16 + ln;
        const float c = acc[mi][ni][r];
        const int b = mrow >> 11, s = mrow & (S_ - 1);
        const int h = ncol >> 6, dk = ncol & 63;
        const size_t o = (((size_t)b * H_ + h) * S_ + s) * DK_ + dk;
        __bf16 hh = (__bf16)c;
        Oh[o] = hh;
        Ol[o] = (__bf16)(c - (float)hh);
      }
}

// ---------------------------------------------------------------------------
// Split-bf16 MFMA GEMM (template kept for V^T MODE2 and out MODE0).
// ---------------------------------------------------------------------------
template <bool AF32, bool BF32, bool LO, int MODE>
__global__ __launch_bounds__(256) void gemm_mfma(
    const void* __restrict__ Ap, const void* __restrict__ Bp, const void* __restrict__ Blop,
    float* __restrict__ Cf, __bf16* __restrict__ Oh, __bf16* __restrict__ Ol) {
  __shared__ __bf16 Ash[64 * 40];
  __shared__ __bf16 Asl[64 * 40];
  __shared__ __bf16 Bsh[64 * 40];
  __shared__ __bf16 Bsl[64 * 40];

  const int tid = threadIdx.x;
  const int m0 = blockIdx.y * 64, n0 = blockIdx.x * 64;
  const int row = tid >> 2, seg = tid & 3;
  const int lane = tid & 63, wv = tid >> 6;
  const int wm = (wv & 1) * 32, wn = (wv >> 1) * 32;
  const int qd = lane >> 4, ln = lane & 15;

  f4 acc[2][2];
#pragma unroll
  for (int i = 0; i < 2; i++)
#pragma unroll
    for (int j = 0; j < 2; j++)
#pragma unroll
      for (int r = 0; r < 4; r++) acc[i][j][r] = 0.f;

  for (int kt = 0; kt < 512; kt += 32) {
    const size_t abase = (size_t)(m0 + row) * 512 + kt + seg * 8;
    const size_t bbase = (size_t)(n0 + row) * 512 + kt + seg * 8;
    float4 a0, a1, b0, b1, bl0;
    if constexpr (AF32) {
      const float* A = (const float*)Ap;
      a0 = *(const float4*)&A[abase];
      a1 = *(const float4*)&A[abase + 4];
    } else {
      const __bf16* A = (const __bf16*)Ap;
      a0 = *(const float4*)&A[abase];
    }
    if constexpr (BF32) {
      const float* Bm = (const float*)Bp;
      b0 = *(const float4*)&Bm[bbase];
      b1 = *(const float4*)&Bm[bbase + 4];
    } else {
      const __bf16* Bm = (const __bf16*)Bp;
      b0 = *(const float4*)&Bm[bbase];
      if constexpr (LO) {
        const __bf16* Bl = (const __bf16*)Blop;
        bl0 = *(const float4*)&Bl[bbase];
      }
    }
    __syncthreads();
    if constexpr (AF32) {
      float x[8] = {a0.x, a0.y, a0.z, a0.w, a1.x, a1.y, a1.z, a1.w};
      bfrag h, l;
#pragma unroll
      for (int j = 0; j < 8; j++) {
        h[j] = (__bf16)x[j];
        l[j] = (__bf16)(x[j] - (float)h[j]);
      }
      *(bfrag*)&Ash[row * 40 + seg * 8] = h;
      if constexpr (LO) *(bfrag*)&Asl[row * 40 + seg * 8] = l;
    } else {
      *(float4*)&Ash[row * 40 + seg * 8] = a0;
    }
    if constexpr (BF32) {
      float x[8] = {b0.x, b0.y, b0.z, b0.w, b1.x, b1.y, b1.z, b1.w};
      bfrag h;
#pragma unroll
      for (int j = 0; j < 8; j++) h[j] = (__bf16)x[j];
      *(bfrag*)&Bsh[row * 40 + seg * 8] = h;
    } else {
      *(float4*)&Bsh[row * 40 + seg * 8] = b0;
      if constexpr (LO) *(float4*)&Bsl[row * 40 + seg * 8] = bl0;
    }
    __syncthreads();

    bfrag ah[2], al[2], bh[2], bl[2];
#pragma unroll
    for (int mi = 0; mi < 2; mi++) {
      ah[mi] = *(bfrag*)&Ash[(wm + mi * 16 + ln) * 40 + qd * 8];
      if constexpr (LO) al[mi] = *(bfrag*)&Asl[(wm + mi * 16 + ln) * 40 + qd * 8];
    }
#pragma unroll
    for (int ni = 0; ni < 2; ni++) {
      bh[ni] = *(bfrag*)&Bsh[(wn + ni * 16 + ln) * 40 + qd * 8];
      if constexpr (LO) bl[ni] = *(bfrag*)&Bsl[(wn + ni * 16 + ln) * 40 + qd * 8];
    }
#pragma unroll
    for (int mi = 0; mi < 2; mi++)
#pragma unroll
      for (int ni = 0; ni < 2; ni++) {
        acc[mi][ni] = MFMA16(ah[mi], bh[ni], acc[mi][ni]);
        if constexpr (LO) {
          acc[mi][ni] = MFMA16(ah[mi], bl[ni], acc[mi][ni]);
          acc[mi][ni] = MFMA16(al[mi], bh[ni], acc[mi][ni]);
        }
      }
  }

#pragma unroll
  for (int mi = 0; mi < 2; mi++)
#pragma unroll
    for (int ni = 0; ni < 2; ni++)
#pragma unroll
      for (int r = 0; r < 4; r++) {
        const int mrow = m0 + wm + mi * 16 + qd * 4 + r;
        const int ncol = n0 + wn + ni * 16 + ln;
        const float c = acc[mi][ni][r];
        if constexpr (MODE == 0) {
          Cf[(size_t)mrow * 512 + ncol] = c;
        } else if constexpr (MODE == 1) {
          const int b = mrow >> 11, s = mrow & (S_ - 1);
          const int h = ncol >> 6, dk = ncol & 63;
          const size_t o = (((size_t)b * H_ + h) * S_ + s) * DK_ + dk;
          __bf16 hh = (__bf16)c;
          Oh[o] = hh;
          Ol[o] = (__bf16)(c - (float)hh);
        } else {  // MODE 2: V^T
          const int h = mrow >> 6, dk = mrow & 63;
          const int b = ncol >> 11, s = ncol & (S_ - 1);
          Oh[(((size_t)b * H_ + h) * DK_ + dk) * S_ + s] = (__bf16)c;
        }
      }
}

// ---------------------------------------------------------------------------
// Fused flash attention — EXACT R4/R10 frozen body (139.5 µs, VGPR 120).
// Refuted levers (measured): occupancy via LDS/VGPR/grid (R2/R3/R7/R11),
// body restructure (R5/R6/R7), exp2f (R8), QBLK amortization (R11: FETCH
// unchanged -> K/V re-fetch was never the cost; 1 block/CU loses the
// inter-block barrier overlap that makes the 2-barrier loop work).
// FROZEN: grid (16,32), 256 thr, SCALE fmaf + __expf + fp8 E.
// ---------------------------------------------------------------------------
__global__ __launch_bounds__(256) void attn_fctx(
    const __bf16* __restrict__ Qh_, const __bf16* __restrict__ Ql_,
    const __bf16* __restrict__ Kh_, const __bf16* __restrict__ Kl_,
    const __bf16* __restrict__ VT, const float* __restrict__ mask,
    __bf16* __restrict__ CTXb, float* __restrict__ MR, float* __restrict__ LR,
    unsigned char* __restrict__ E, float* __restrict__ MT) {
  __shared__ __bf16 Ksh[64 * KSTR];
  __shared__ __bf16 Ksl[64 * KSTR];
  __shared__ __bf16 Vs[64 * KSTR];
  __shared__ __bf16 Ps[128 * PSTR];
  __shared__ float als[128];
  const int tid = threadIdx.x, lane = tid & 63, wv = tid >> 6;
  const int l31 = lane & 31, kh = lane >> 5;
  const int qd = lane >> 4, ln = lane & 15;
  const int bh = blockIdx.y;
  const int q0b = blockIdx.x * 128;
  const int q0w = q0b + wv * 32;
  const int srow = tid >> 2, sseg = tid & 3;

  // Q fragments (B-operand, 32x32x16): n = q = l31, k = ks*16 + kh*8 + j
  bfrag qhf[4], qlf[4];
#pragma unroll
  for (int ks = 0; ks < 4; ks++) {
    const size_t qb = ((size_t)bh * S_ + q0w + l31) * DK_ + ks * 16 + kh * 8;
    qhf[ks] = *(const bfrag*)&Qh_[qb];
    qlf[ks] = *(const bfrag*)&Ql_[qb];
  }

  float m = -3.0e38f, l = 0.f;   // per lane: q = q0w + l31 (dup across halves)
  f4 cacc[2][4];                  // [mt][nt] — PV 16-shape accumulators
#pragma unroll
  for (int mt = 0; mt < 2; mt++)
#pragma unroll
    for (int nt = 0; nt < 4; nt++)
#pragma unroll
      for (int r = 0; r < 4; r++) cacc[mt][nt][r] = 0.f;

  // prefetch tile 0
  float4 h0, h1, l0, l1, v0, v1;
  {
    const size_t kb = ((size_t)bh * S_ + srow) * DK_ + sseg * 16;
    const size_t vb = ((size_t)bh * DK_ + srow) * S_ + sseg * 16;
    h0 = *(const float4*)&Kh_[kb]; h1 = *(const float4*)&Kh_[kb + 8];
    l0 = *(const float4*)&Kl_[kb]; l1 = *(const float4*)&Kl_[kb + 8];
    v0 = *(const float4*)&VT[vb];  v1 = *(const float4*)&VT[vb + 8];
  }

  for (int kt = 0; kt < S_; kt += 64) {
    __syncthreads();
    *(float4*)&Ksh[srow * KSTR + sseg * 16] = h0;
    *(float4*)&Ksh[srow * KSTR + sseg * 16 + 8] = h1;
    *(float4*)&Ksl[srow * KSTR + sseg * 16] = l0;
    *(float4*)&Ksl[srow * KSTR + sseg * 16 + 8] = l1;
    *(float4*)&Vs[srow * KSTR + sseg * 16] = v0;
    *(float4*)&Vs[srow * KSTR + sseg * 16 + 8] = v1;
    __syncthreads();

    // mask, transposed order: entry (q = q0w+l31, kv = kt + t*32 + g*8 + 4*kh + i)
    f4 mk[2][4];
#pragma unroll
    for (int t = 0; t < 2; t++)
#pragma unroll
      for (int g = 0; g < 4; g++)
        mk[t][g] = *(const f4*)&mask[(size_t)(q0w + l31) * S_ + kt + t * 32 + g * 8 + 4 * kh];

    // prefetch next tile
    if (kt + 64 < S_) {
      const size_t kb = ((size_t)bh * S_ + kt + 64 + srow) * DK_ + sseg * 16;
      const size_t vb = ((size_t)bh * DK_ + srow) * S_ + kt + 64 + sseg * 16;
      h0 = *(const float4*)&Kh_[kb]; h1 = *(const float4*)&Kh_[kb + 8];
      l0 = *(const float4*)&Kl_[kb]; l1 = *(const float4*)&Kl_[kb + 8];
      v0 = *(const float4*)&VT[vb];  v1 = *(const float4*)&VT[vb + 8];
    }

    // ---- z^T = K·Q^T, 32x32x16 split-3: 16 b128 reads, 24 MFMAs, 32 q ----
    f16v z[2];
#pragma unroll
    for (int t = 0; t < 2; t++)
#pragma unroll
      for (int r = 0; r < 16; r++) z[t][r] = 0.f;
#pragma unroll
    for (int t = 0; t < 2; t++)
#pragma unroll
      for (int ks = 0; ks < 4; ks++) {
        bfrag kbh = *(bfrag*)&Ksh[(t * 32 + l31) * KSTR + ks * 16 + kh * 8];
        bfrag kbl = *(bfrag*)&Ksl[(t * 32 + l31) * KSTR + ks * 16 + kh * 8];
        z[t] = MFMA32(kbh, qhf[ks], z[t]);
        z[t] = MFMA32(kbl, qhf[ks], z[t]);
        z[t] = MFMA32(kbh, qlf[ks], z[t]);
      }

    // ---- scale + mask in place ----
#pragma unroll
    for (int t = 0; t < 2; t++)
#pragma unroll
      for (int r = 0; r < 16; r++)
        z[t][r] = fmaf(z[t][r], SCALE, mk[t][r >> 2][r & 3]);

    // ---- online softmax: per-lane q column, 1 cross-lane reduce ----
    float tm = z[0][0];
#pragma unroll
    for (int t = 0; t < 2; t++)
#pragma unroll
      for (int r = 0; r < 16; r++) tm = fmaxf(tm, z[t][r]);
    tm = fmaxf(tm, __shfl_xor(tm, 32, 64));
    const float nm = fmaxf(m, tm);
    const float al = __expf(m - nm);
    m = nm;
    if (lane < 32) als[wv * 32 + lane] = al;

    float ls = 0.f;
#pragma unroll
    for (int t = 0; t < 2; t++)
#pragma unroll
      for (int g = 0; g < 4; g++) {
        const float e0 = __expf(z[t][g * 4 + 0] - nm);
        const float e1 = __expf(z[t][g * 4 + 1] - nm);
        const float e2 = __expf(z[t][g * 4 + 2] - nm);
        const float e3 = __expf(z[t][g * 4 + 3] - nm);
        ls += (e0 + e1) + (e2 + e3);
        b4 pk;
        pk[0] = (__bf16)e0; pk[1] = (__bf16)e1;
        pk[2] = (__bf16)e2; pk[3] = (__bf16)e3;
        *(b4*)&Ps[(wv * 32 + l31) * PSTR + t * 32 + g * 8 + 4 * kh] = pk;
      }
    l = l * al + ls;

    if (lane < 32)
      MT[((size_t)bh * 32 + (kt >> 6)) * S_ + q0w + lane] = m;

    // ---- rescale cacc with alpha from LDS (row q = mt*16 + qd*4 + r) ----
#pragma unroll
    for (int mt = 0; mt < 2; mt++) {
      f4 av = *(f4*)&als[wv * 32 + mt * 16 + qd * 4];
#pragma unroll
      for (int nt = 0; nt < 4; nt++)
#pragma unroll
        for (int r = 0; r < 4; r++) cacc[mt][nt][r] *= av[r];
    }

    // ---- PV (16 MFMA, 16-shape): P m=q (2 tiles), V n=d (4 tiles), k=kv ----
    bfrag pa[2][2];
#pragma unroll
    for (int mt = 0; mt < 2; mt++)
#pragma unroll
      for (int ks = 0; ks < 2; ks++)
        pa[mt][ks] = *(bfrag*)&Ps[(wv * 32 + mt * 16 + ln) * PSTR + ks * 32 + qd * 8];
#pragma unroll
    for (int nt = 0; nt < 4; nt++)
#pragma unroll
      for (int ks = 0; ks < 2; ks++) {
        bfrag vbf = *(bfrag*)&Vs[(nt * 16 + ln) * KSTR + ks * 32 + qd * 8];
#pragma unroll
        for (int mt = 0; mt < 2; mt++)
          cacc[mt][nt] = MFMA16(pa[mt][ks], vbf, cacc[mt][nt]);
      }

    // ---- E copy: Ps rows -> global fp8 e4m3 (vectorized, coalesced) ----
#pragma unroll
    for (int c = 0; c < 4; c++) {
      const int row = wv * 32 + (lane >> 3) + c * 8;
      const int ch = lane & 7;
      bfrag pv = *(bfrag*)&Ps[row * PSTR + ch * 8];
      int lo = 0, hi = 0;
      lo = __builtin_amdgcn_cvt_pk_fp8_f32((float)pv[0], (float)pv[1], lo, 0);
      lo = __builtin_amdgcn_cvt_pk_fp8_f32((float)pv[2], (float)pv[3], lo, 1);
      hi = __builtin_amdgcn_cvt_pk_fp8_f32((float)pv[4], (float)pv[5], hi, 0);
      hi = __builtin_amdgcn_cvt_pk_fp8_f32((float)pv[6], (float)pv[7], hi, 1);
      u2 ev;
      ev.x = (unsigned int)lo;
      ev.y = (unsigned int)hi;
      __builtin_nontemporal_store(
          ev, (u2*)&E[((size_t)bh * S_ + q0b + row) * S_ + kt + ch * 8]);
    }
  }

  // ---- epilogue ----
  l += __shfl_xor(l, 32, 64);
  if (lane < 32) {
    MR[(size_t)bh * S_ + q0w + lane] = m;
    LR[(size_t)bh * S_ + q0w + lane] = l;
    als[wv * 32 + lane] = 1.0f / l;
  }
  const int b = bh >> 3, h = bh & 7;
#pragma unroll
  for (int mt = 0; mt < 2; mt++) {
    f4 iv = *(f4*)&als[wv * 32 + mt * 16 + qd * 4];
#pragma unroll
    for (int nt = 0; nt < 4; nt++)
#pragma unroll
      for (int r = 0; r < 4; r++)
        CTXb[((size_t)b * S_ + q0w + mt * 16 + qd * 4 + r) * D_ + h * DK_ + nt * 16 + ln] =
            (__bf16)(cacc[mt][nt][r] * iv[r]);
  }
}

// ---------------------------------------------------------------------------
// mean = (1/8) sum_h E * exp(MT - m_fin) / l_fin  — bandwidth kernel.
// R8's coalesced layout (verified, ~20 µs gain): block = 8 q x 32 k-segments;
// each lane loads 16 B of E -> 512 B contiguous per wave per head; writes
// 16 f32/lane -> 2 KB contiguous per wave. Grid (S/8, B, S/512).
// E fp8 e4m3; MT/MR natural-log domain. Traffic is already minimal
// (each E byte read once, mean written once): ~201 MB -> ~33 µs floor.
// ---------------------------------------------------------------------------
__global__ __launch_bounds__(256) void mean_rescale(
    const unsigned char* __restrict__ E, const float* __restrict__ MT,
    const float* __restrict__ MR, const float* __restrict__ LR,
    float* __restrict__ meanout) {
  const int t = threadIdx.x;
  const int qr = t >> 5, sk = t & 31;
  const int b = blockIdx.y;
  const int qg = blockIdx.x * 8 + qr;
  const int k0 = blockIdx.z * 512 + sk * 16;
  const int tk = k0 >> 6;

  float acc[16];
#pragma unroll
  for (int j = 0; j < 16; j++) acc[j] = 0.f;

#pragma unroll
  for (int h = 0; h < H_; h++) {
    const int bh = b * H_ + h;
    const float mf = MR[(size_t)bh * S_ + qg];
    const float il = 1.0f / LR[(size_t)bh * S_ + qg];
    const float mt = MT[((size_t)bh * 32 + tk) * S_ + qg];
    const float sc = __expf(mt - mf) * il;
    u4 e = __builtin_nontemporal_load(
        (const u4*)&E[((size_t)bh * S_ + qg) * S_ + k0]);
#pragma unroll
    for (int wd = 0; wd < 4; wd++) {
      f2 plo = __builtin_amdgcn_cvt_pk_f32_fp8((int)e[wd], 0);
      f2 phi = __builtin_amdgcn_cvt_pk_f32_fp8((int)e[wd], 1);
      acc[wd * 4 + 0] += plo.x * sc;
      acc[wd * 4 + 1] += plo.y * sc;
      acc[wd * 4 + 2] += phi.x * sc;
      acc[wd * 4 + 3] += phi.y * sc;
    }
  }

  float* mp = &meanout[((size_t)b * S_ + qg) * S_ + k0];
#pragma unroll
  for (int wd = 0; wd < 4; wd++) {
    f4 o;
    o[0] = acc[wd * 4 + 0] * 0.125f;
    o[1] = acc[wd * 4 + 1] * 0.125f;
    o[2] = acc[wd * 4 + 2] * 0.125f;
    o[3] = acc[wd * 4 + 3] * 0.125f;
    *(f4*)&mp[wd * 4] = o;
  }
}

// ---------------------------------------------------------------------------
extern "C" void kernel_launch(void* const* d_in, const int* in_sizes, int n_in,
                              void* d_out, int out_size, void* d_ws, size_t ws_size,
                              hipStream_t stream) {
  (void)in_sizes; (void)n_in; (void)out_size; (void)ws_size;
  const float* Zq = (const float*)d_in[0];
  const float* Zkv = (const float*)d_in[1];
  const float* mask = (const float*)d_in[2];
  const float* Wqkv = (const float*)d_in[3];
  const float* Wout = (const float*)d_in[4];

  float* out = (float*)d_out;                // [B,S,D]
  float* mean = out + (size_t)B_ * S_ * D_;  // [B,S,S]

  char* w = (char*)d_ws;
  const size_t WSZ = 512 * 512 * sizeof(__bf16);
  const size_t QSZ = (size_t)B_ * H_ * S_ * DK_ * sizeof(__bf16);
  __bf16* WqTh = (__bf16*)w; w += WSZ;
  __bf16* WqTl = (__bf16*)w; w += WSZ;
  __bf16* WkTh = (__bf16*)w; w += WSZ;
  __bf16* WkTl = (__bf16*)w; w += WSZ;
  __bf16* WvTh = (__bf16*)w; w += WSZ;
  __bf16* WoTh = (__bf16*)w; w += WSZ;
  __bf16* Qh = (__bf16*)w; w += QSZ;
  __bf16* Ql = (__bf16*)w; w += QSZ;
  __bf16* Kh = (__bf16*)w; w += QSZ;
  __bf16* Kl = (__bf16*)w; w += QSZ;
  __bf16* VTh = (__bf16*)w; w += QSZ;
  __bf16* CTXb = (__bf16*)w; w += QSZ;
  float* MR = (float*)w; w += (size_t)B_ * H_ * S_ * sizeof(float);
  float* LR = (float*)w; w += (size_t)B_ * H_ * S_ * sizeof(float);
  float* MT = (float*)w; w += (size_t)B_ * H_ * 32 * S_ * sizeof(float);       // 8.4 MB
  unsigned char* E = (unsigned char*)w; w += (size_t)B_ * H_ * S_ * S_;        // 134 MB (fp8)

  wtr_all<<<dim3(1024, 4), 256, 0, stream>>>(Wqkv, Wout, WqTh, WqTl, WkTh, WkTl, WvTh, WoTh);

  qk_proj<<<dim3(8, 128, 2), 256, 0, stream>>>(
      Zq, Zkv, WqTh, WqTl, WkTh, WkTl, Qh, Ql, Kh, Kl);
  gemm_mfma<false, true, false, 2><<<dim3(128, 8), 256, 0, stream>>>(
      WvTh, Zkv, nullptr, nullptr, VTh, nullptr);

  attn_fctx<<<dim3(16, 32), 256, 0, stream>>>(Qh, Ql, Kh, Kl, VTh, mask, CTXb, MR, LR, E, MT);
  mean_rescale<<<dim3(256, 4, 4), 256, 0, stream>>>(E, MT, MR, LR, mean);

  gemm_mfma<false, false, false, 0><<<dim3(8, 128), 256, 0, stream>>>(
      CTXb, WoTh, nullptr, out, nullptr, nullptr);
}